// Round 13
// baseline (200.695 us; speedup 1.0000x reference)
//
#include <hip/hip_runtime.h>
#include <hip/hip_bf16.h>

// ---------------------------------------------------------------------------
// GQA block: y = Attn(x Wq + bq, x Wk + bk, x Wv + bv) Wo + bo
// B=2 S=2048 E=2048 H=16 G=4 D=128 R=4.  All GEMMs in bf16 MFMA, fp32 accum.
// R1: swapped QK^T attention (P in-register), V pre-transpose, defer-max.
// R2: GEMM 8-wave pipeline, 4-deep LDS ring, counted vmcnt, raw s_barrier.
// R3: QKV GEMM 256x192 (grid 256); attn K/V dbuf 64KB (1 barrier).
// R4-R9: six attn occupancy/staging variants regressed; R3 attn = optimum.
// R10: no-max softmax; V-transpose fused into QKV GEMM. [attn 82.2, tot 190.7]
// R11: LDS swizzle NEUTRAL -> conflict diagnosis retracted (frag reads are
//     contiguous-1KB, conflict-free by construction). Swizzle dropped.
// R12: GEMM K-loop ported to m201-style phase schedule (T3): per K-tile,
//     NPH phases {2 A-frag ds_reads | 1 stage-group | barrier | lgkmcnt(0) |
//     setprio | MFMA cluster | setprio | barrier}; B-frags in P0; counted
//     vmcnt(LOADS) only at each tile's last phase. Geometry unchanged.
// ---------------------------------------------------------------------------

typedef __attribute__((ext_vector_type(8))) short bf16x8;
typedef __attribute__((ext_vector_type(4))) short bf16x4;
typedef __attribute__((ext_vector_type(4))) float f32x4;

#define MFMA_16x16x32(a, b, c) __builtin_amdgcn_mfma_f32_16x16x32_bf16((a), (b), (c), 0, 0, 0)

__device__ __forceinline__ unsigned short f2bf(float x) {
  union { float f; unsigned int u; } c;
  c.f = x;
  unsigned int u = c.u;
  return (unsigned short)((u + 0x7fffu + ((u >> 16) & 1u)) >> 16);  // RNE
}

__device__ __forceinline__ unsigned short f2bf_hw(float x) {
  __hip_bfloat16 h = __float2bfloat16(x);
  union { __hip_bfloat16 h; unsigned short u; } c;
  c.h = h;
  return c.u;
}

__device__ __forceinline__ void gload_lds16(const void* g, void* l) {
  __builtin_amdgcn_global_load_lds(
      (const __attribute__((address_space(1))) unsigned int*)g,
      (__attribute__((address_space(3))) unsigned int*)l, 16, 0, 0);
}

// ---------------------------------------------------------------------------
// cast fp32 -> bf16, 8 elems/thread
__global__ void cast_x_kernel(const float* __restrict__ x,
                              unsigned short* __restrict__ out, long n) {
  long i = ((long)blockIdx.x * blockDim.x + threadIdx.x) * 8;
  if (i >= n) return;
  float4 a = *reinterpret_cast<const float4*>(x + i);
  float4 b = *reinterpret_cast<const float4*>(x + i + 4);
  union { unsigned short s[8]; bf16x8 v; } o;
  o.s[0] = f2bf(a.x); o.s[1] = f2bf(a.y); o.s[2] = f2bf(a.z); o.s[3] = f2bf(a.w);
  o.s[4] = f2bf(b.x); o.s[5] = f2bf(b.y); o.s[6] = f2bf(b.z); o.s[7] = f2bf(b.w);
  *reinterpret_cast<bf16x8*>(out + i) = o.v;
}

// All four weight transposes in one launch.
__global__ void prep_w_kernel(const float* __restrict__ Wq,
                              const float* __restrict__ Wk,
                              const float* __restrict__ Wv,
                              const float* __restrict__ Wo,
                              unsigned short* __restrict__ WqkvT,
                              unsigned short* __restrict__ WoT) {
  __shared__ float t[32][33];
  const int tx = threadIdx.x, ty = threadIdx.y;
  const int ng = blockIdx.x * 32;
  const int k0 = blockIdx.y * 32;
  const float* src;
  int srcN, n0;
  unsigned short* dst;
  if (ng < 2048)      { src = Wq; srcN = 2048; n0 = ng;        dst = WqkvT + (size_t)ng * 2048; }
  else if (ng < 2560) { src = Wk; srcN = 512;  n0 = ng - 2048; dst = WqkvT + (size_t)ng * 2048; }
  else if (ng < 3072) { src = Wv; srcN = 512;  n0 = ng - 2560; dst = WqkvT + (size_t)ng * 2048; }
  else                { src = Wo; srcN = 2048; n0 = ng - 3072; dst = WoT + (size_t)(ng - 3072) * 2048; }
#pragma unroll
  for (int i = 0; i < 4; i++)
    t[ty + i * 8][tx] = src[(size_t)(k0 + ty + i * 8) * srcN + n0 + tx];
  __syncthreads();
#pragma unroll
  for (int i = 0; i < 4; i++)
    dst[(size_t)(ty + i * 8) * 2048 + k0 + tx] = f2bf(t[tx][ty + i * 8]);
}

__global__ void concat_bias_kernel(const float* __restrict__ bq,
                                   const float* __restrict__ bk,
                                   const float* __restrict__ bv,
                                   float* __restrict__ out) {
  int i = blockIdx.x * 256 + threadIdx.x;
  if (i >= 3072) return;
  out[i] = (i < 2048) ? bq[i] : (i < 2560 ? bk[i - 2048] : bv[i - 2560]);
}

// ---------------------------------------------------------------------------
// Phase-scheduled pipelined GEMM (T3+T4): ring-4 LDS, 2-ahead prefetch.
// Per K-tile: NPH phases, each {A-frag ds_reads | stage-group | s_barrier |
// lgkmcnt(0) | setprio1 | MFMA cluster | setprio0 | s_barrier}; B-frags read
// in phase 0; vmcnt(LOADS) only at the tile's last phase (0 at tail).
// For the QKV instance (vt != nullptr), columns gc >= 2560 are V: written
// (with kv-permutation c()) to vt instead of C.
template <int AROWS, int BROWS, bool BF16OUT>
__global__ __launch_bounds__(512, 2)
void gemm_pipe_kernel(const unsigned short* __restrict__ A,
                      const unsigned short* __restrict__ Bt,
                      const float* __restrict__ bias,
                      void* __restrict__ C, int M, int N, int K,
                      float qscale, int qcols,
                      unsigned short* __restrict__ vt) {
  constexpr int FM = AROWS / 32;
  constexpr int FN = BROWS / 64;
  constexpr int TC = (AROWS + BROWS) * 4;
  constexpr int LOADS = (TC + 511) / 512;
  constexpr int PC = LOADS * 512;
  constexpr int BUFE = PC * 8;
  constexpr int BOFF = AROWS * 32;
  constexpr int NPH = (FM >= 8) ? 4 : 2;   // phases per K-tile
  constexpr int RPP = FM / NPH;            // 16-row frags per phase
  __shared__ unsigned short lds[4 * BUFE];

  const int tid = threadIdx.x;
  const int w = tid >> 6, l = tid & 63, lg = l >> 4, ll = l & 15;
  const int wm = w >> 2, wn = w & 3;
  const int m0 = blockIdx.y * AROWS;
  const int n0 = blockIdx.x * BROWS;
  const int NT = K >> 5;

  const f32x4 fz = {0.f, 0.f, 0.f, 0.f};
  f32x4 acc[FM][FN];
#pragma unroll
  for (int i = 0; i < FM; i++)
#pragma unroll
    for (int j = 0; j < FN; j++) acc[i][j] = fz;

  const unsigned short* gsrc[LOADS];
#pragma unroll
  for (int i = 0; i < LOADS; ++i) {
    const int c = tid + 512 * i;
    if (c < AROWS * 4) {
      gsrc[i] = A + (size_t)(m0 + (c >> 2)) * K + (c & 3) * 8;
    } else if (c < TC) {
      const int cb = c - AROWS * 4;
      gsrc[i] = Bt + (size_t)(n0 + (cb >> 2)) * K + (cb & 3) * 8;
    } else {
      gsrc[i] = Bt + (size_t)n0 * K;  // dummy, lands in pad region
    }
  }

  // prologue: fully stage tiles 0 and 1
#pragma unroll
  for (int g = 0; g < LOADS; ++g)
    gload_lds16(gsrc[g], &lds[tid * 8 + g * 4096]);
#pragma unroll
  for (int g = 0; g < LOADS; ++g)
    gload_lds16(gsrc[g] + 32, &lds[BUFE + tid * 8 + g * 4096]);
  if constexpr (LOADS == 4)
    asm volatile("s_waitcnt vmcnt(4)" ::: "memory");
  else
    asm volatile("s_waitcnt vmcnt(3)" ::: "memory");
  __builtin_amdgcn_s_barrier();

  for (int t = 0; t < NT; ++t) {
    const unsigned short* bufp = &lds[(t & 3) * BUFE];
    unsigned short* sdst = &lds[((t + 2) & 3) * BUFE + tid * 8];
    const bool dostage = (t + 2 < NT);
    bf16x8 bfrag[FN];
#pragma unroll
    for (int p = 0; p < NPH; ++p) {
      if (p == 0) {
#pragma unroll
        for (int ni = 0; ni < FN; ++ni)
          bfrag[ni] = *reinterpret_cast<const bf16x8*>(
              &bufp[BOFF + (wn * FN * 16 + ni * 16 + ll) * 32 + lg * 8]);
      }
      bf16x8 afrag[RPP];
#pragma unroll
      for (int r = 0; r < RPP; ++r)
        afrag[r] = *reinterpret_cast<const bf16x8*>(
            &bufp[(wm * (AROWS / 2) + (p * RPP + r) * 16 + ll) * 32 + lg * 8]);
      if (dostage) {
        if constexpr (NPH == 4) {
          if (p < LOADS)
            gload_lds16(gsrc[p] + (t + 2) * 32, sdst + p * 4096);
        } else {
          if (p == 0) {
            gload_lds16(gsrc[0] + (t + 2) * 32, sdst);
            gload_lds16(gsrc[1] + (t + 2) * 32, sdst + 4096);
          } else {
#pragma unroll
            for (int g = 2; g < LOADS; ++g)
              gload_lds16(gsrc[g] + (t + 2) * 32, sdst + g * 4096);
          }
        }
      }
      __builtin_amdgcn_s_barrier();
      asm volatile("s_waitcnt lgkmcnt(0)" ::: "memory");
      __builtin_amdgcn_s_setprio(1);
#pragma unroll
      for (int r = 0; r < RPP; ++r)
#pragma unroll
        for (int ni = 0; ni < FN; ++ni)
          acc[p * RPP + r][ni] =
              MFMA_16x16x32(afrag[r], bfrag[ni], acc[p * RPP + r][ni]);
      __builtin_amdgcn_s_setprio(0);
      if (p == NPH - 1 && t + 1 < NT) {
        if (dostage) {
          if constexpr (LOADS == 4)
            asm volatile("s_waitcnt vmcnt(4)" ::: "memory");
          else
            asm volatile("s_waitcnt vmcnt(3)" ::: "memory");
        } else {
          asm volatile("s_waitcnt vmcnt(0)" ::: "memory");
        }
      }
      __builtin_amdgcn_s_barrier();
    }
  }

#pragma unroll
  for (int mi = 0; mi < FM; ++mi) {
#pragma unroll
    for (int ni = 0; ni < FN; ++ni) {
      const int gc = n0 + wn * FN * 16 + ni * 16 + ll;
      const float bv = bias[gc];
      const float sc = (gc < qcols) ? qscale : 1.0f;
      if (BF16OUT && vt != nullptr && gc >= 2560) {
        // V column: write to Vt[(b*512 + d)][sp(s)] with c() permutation
        const int gr0 = m0 + wm * (AROWS / 2) + mi * 16 + 4 * lg;
        const int bb = gr0 >> 11, s = gr0 & 2047;
        const int spb = (s & ~63) | ((s & 12) << 1) | (((s >> 4) & 1) << 2) | (s & 32);
        union { unsigned short u[4]; bf16x4 v4; } ov;
#pragma unroll
        for (int r = 0; r < 4; ++r) ov.u[r] = f2bf(acc[mi][ni][r] + bv);
        *reinterpret_cast<bf16x4*>(
            &vt[(size_t)(bb * 512 + gc - 2560) * 2048 + spb]) = ov.v4;
      } else {
#pragma unroll
        for (int r = 0; r < 4; ++r) {
          const int gr = m0 + wm * (AROWS / 2) + mi * 16 + 4 * lg + r;
          const float v = (acc[mi][ni][r] + bv) * sc;
          if constexpr (BF16OUT)
            ((unsigned short*)C)[(size_t)gr * N + gc] = f2bf(v);
          else
            ((float*)C)[(size_t)gr * N + gc] = v;
        }
      }
    }
  }
}

// ---------------------------------------------------------------------------
// Flash attention (R10, unchanged): 4 waves x 32 q, KVBLK=64, grid (16,32).
// K/V dbuf 64KB (reg-staged, 1 barrier/tile). QKV row stride 2560. No-max
// softmax: p = exp2(s) raw; lane-local lsum reduced once in epilogue.
__global__ __launch_bounds__(256, 2)
void attn_kernel(const unsigned short* __restrict__ QKV,
                 const unsigned short* __restrict__ Vt,
                 unsigned short* __restrict__ AO) {
  __shared__ unsigned short Klds[2][64 * 128];  // [kv][d]  elem ^ ((kv&7)<<3)
  __shared__ unsigned short Vlds[2][128 * 64];  // [d][c]   elem ^ ((d&7)<<3)

  const int tid = threadIdx.x;
  const int w = tid >> 6, l = tid & 63, lg = l >> 4, ll = l & 15;
  const int bh = blockIdx.y;
  const int b = bh >> 4, h = bh & 15, g = h >> 2;
  const int q0 = blockIdx.x * 128 + w * 32;
  const size_t row_base = (size_t)b * 2048 * 2560;
  const unsigned short* Vg = Vt + (size_t)(b * 512 + g * 128) * 2048;

  bf16x8 qf[2][4];
#pragma unroll
  for (int mi = 0; mi < 2; mi++)
#pragma unroll
    for (int ds = 0; ds < 4; ds++)
      qf[mi][ds] = *reinterpret_cast<const bf16x8*>(
          QKV + row_base + (size_t)(q0 + mi * 16 + ll) * 2560 + h * 128 + ds * 32 + 8 * lg);

  const f32x4 fz = {0.f, 0.f, 0.f, 0.f};
  f32x4 o[8][2];
#pragma unroll
  for (int di = 0; di < 8; di++)
#pragma unroll
    for (int mi = 0; mi < 2; mi++) o[di][mi] = fz;
  float pssum[2] = {0.f, 0.f};

  const int krow = tid >> 4, kc8 = tid & 15;
  const int vrow = tid >> 3, vc8 = tid & 7;
  const unsigned short* Kg = QKV + row_base + 2048 + g * 128 + kc8 * 8 + (size_t)krow * 2560;
  int klo[4], vlo[4];
#pragma unroll
  for (int i = 0; i < 4; i++) {
    const int kr = krow + 16 * i;
    klo[i] = (kr * 128 + kc8 * 8) ^ ((kr & 7) << 3);
    const int vr = vrow + 32 * i;
    vlo[i] = (vr * 64 + vc8 * 8) ^ ((vr & 7) << 3);
  }

  bf16x8 kreg[4], vreg[4];
#pragma unroll
  for (int i = 0; i < 4; i++) {
    kreg[i] = *reinterpret_cast<const bf16x8*>(Kg + (size_t)(16 * i) * 2560);
    vreg[i] = *reinterpret_cast<const bf16x8*>(Vg + (size_t)(vrow + 32 * i) * 2048 + vc8 * 8);
  }

  for (int kt = 0; kt < 32; kt++) {
    const int cb = kt & 1;
#pragma unroll
    for (int i = 0; i < 4; i++) *reinterpret_cast<bf16x8*>(&Klds[cb][klo[i]]) = kreg[i];
#pragma unroll
    for (int i = 0; i < 4; i++) *reinterpret_cast<bf16x8*>(&Vlds[cb][vlo[i]]) = vreg[i];
    __syncthreads();

    if (kt + 1 < 32) {
#pragma unroll
      for (int i = 0; i < 4; i++) {
        kreg[i] = *reinterpret_cast<const bf16x8*>(
            Kg + (size_t)((kt + 1) * 64 + 16 * i) * 2560);
        vreg[i] = *reinterpret_cast<const bf16x8*>(
            Vg + (size_t)(vrow + 32 * i) * 2048 + (kt + 1) * 64 + vc8 * 8);
      }
    }

    f32x4 st[4][2];
#pragma unroll
    for (int ni = 0; ni < 4; ni++)
#pragma unroll
      for (int mi = 0; mi < 2; mi++) st[ni][mi] = fz;
#pragma unroll
    for (int ds = 0; ds < 4; ds++) {
      bf16x8 kf[4];
#pragma unroll
      for (int ni = 0; ni < 4; ni++) {
        const int kr = ni * 16 + ll;
        kf[ni] = *reinterpret_cast<const bf16x8*>(
            &Klds[cb][(kr * 128 + ds * 32 + 8 * lg) ^ ((kr & 7) << 3)]);
      }
      __builtin_amdgcn_s_setprio(1);
#pragma unroll
      for (int ni = 0; ni < 4; ni++)
#pragma unroll
        for (int mi = 0; mi < 2; mi++)
          st[ni][mi] = MFMA_16x16x32(kf[ni], qf[mi][ds], st[ni][mi]);
      __builtin_amdgcn_s_setprio(0);
    }

#pragma unroll
    for (int ni = 0; ni < 4; ni++)
#pragma unroll
      for (int mi = 0; mi < 2; mi++)
#pragma unroll
        for (int r = 0; r < 4; r++) {
          const float pv = __builtin_amdgcn_exp2f(st[ni][mi][r]);
          st[ni][mi][r] = pv;
          pssum[mi] += pv;
        }

    bf16x8 pf[2][2];
#pragma unroll
    for (int mi = 0; mi < 2; mi++)
#pragma unroll
      for (int ks = 0; ks < 2; ks++)
#pragma unroll
        for (int j = 0; j < 4; j++) {
          pf[mi][ks][j]     = (short)f2bf_hw(st[2 * ks][mi][j]);
          pf[mi][ks][4 + j] = (short)f2bf_hw(st[2 * ks + 1][mi][j]);
        }

    __builtin_amdgcn_s_setprio(1);
#pragma unroll
    for (int ks = 0; ks < 2; ks++)
#pragma unroll
      for (int di = 0; di < 8; di++) {
        const int dr = di * 16 + ll;
        const bf16x8 vf = *reinterpret_cast<const bf16x8*>(
            &Vlds[cb][(dr * 64 + ks * 32 + 8 * lg) ^ ((dr & 7) << 3)]);
        o[di][0] = MFMA_16x16x32(vf, pf[0][ks], o[di][0]);
        o[di][1] = MFMA_16x16x32(vf, pf[1][ks], o[di][1]);
      }
    __builtin_amdgcn_s_setprio(0);
  }

  float invl[2];
#pragma unroll
  for (int mi = 0; mi < 2; mi++) {
    float s = pssum[mi];
    s += __shfl_xor(s, 16, 64);
    s += __shfl_xor(s, 32, 64);
    invl[mi] = 1.0f / s;
  }
#pragma unroll
  for (int mi = 0; mi < 2; mi++) {
    const size_t rowoff = (size_t)(b * 2048 + q0 + mi * 16 + ll) * 2048 + h * 128;
#pragma unroll
    for (int di = 0; di < 8; di++) {
      union { unsigned short s[4]; bf16x4 v; } ov;
#pragma unroll
      for (int r = 0; r < 4; r++) ov.s[r] = f2bf_hw(o[di][mi][r] * invl[mi]);
      *reinterpret_cast<bf16x4*>(&AO[rowoff + di * 16 + 4 * lg]) = ov.v;
    }
  }
}

// ---------------------------------------------------------------------------
extern "C" void kernel_launch(void* const* d_in, const int* in_sizes, int n_in,
                              void* d_out, int out_size, void* d_ws, size_t ws_size,
                              hipStream_t stream) {
  const float* x  = (const float*)d_in[0];
  const float* Wq = (const float*)d_in[1];
  const float* bq = (const float*)d_in[2];
  const float* Wk = (const float*)d_in[3];
  const float* bk = (const float*)d_in[4];
  const float* Wv = (const float*)d_in[5];
  const float* bv = (const float*)d_in[6];
  const float* Wo = (const float*)d_in[7];
  const float* bo = (const float*)d_in[8];
  float* out = (float*)d_out;

  // workspace carve (bf16 elems), total ~76 MB:
  unsigned short* xb    = (unsigned short*)d_ws;               // 4096*2048
  unsigned short* WqkvT = xb + (size_t)4096 * 2048;            // 3072*2048
  unsigned short* WoT   = WqkvT + (size_t)3072 * 2048;         // 2048*2048
  unsigned short* QKV   = WoT + (size_t)2048 * 2048;           // 4096*2560 (Q|K only)
  unsigned short* AO    = QKV + (size_t)4096 * 2560;           // 4096*2048
  unsigned short* Vt    = AO + (size_t)4096 * 2048;            // 1024*2048
  float* bqkv = (float*)(Vt + (size_t)1024 * 2048);            // 3072 f32

  const float QSC2 = 0.08838834764831845f * 1.4426950408889634f;  // 1/sqrt(D)*log2e

  cast_x_kernel<<<4096, 256, 0, stream>>>(x, xb, (long)8388608);
  prep_w_kernel<<<dim3(160, 64), dim3(32, 8), 0, stream>>>(Wq, Wk, Wv, Wo, WqkvT, WoT);
  concat_bias_kernel<<<12, 256, 0, stream>>>(bq, bk, bv, bqkv);

  // QKV GEMM: Q,K -> QKV (stride 2560, Q pre-scaled by QSC2); V -> Vt fused.
  gemm_pipe_kernel<256, 192, true><<<dim3(16, 16), 512, 0, stream>>>(
      xb, WqkvT, bqkv, QKV, 4096, 2560, 2048, QSC2, 2048, Vt);
  // flash attention -> AO bf16 [4096][2048]
  attn_kernel<<<dim3(16, 32), 256, 0, stream>>>(QKV, Vt, AO);
  // out = AO @ WoT^T + bo -> fp32
  gemm_pipe_kernel<128, 256, false><<<dim3(8, 32), 512, 0, stream>>>(
      AO, WoT, bo, out, 4096, 2048, 2048, 1.0f, 0, nullptr);
}

// Round 14
// 186.520 us; speedup vs baseline: 1.0760x; 1.0760x over previous
//
#include <hip/hip_runtime.h>
#include <hip/hip_bf16.h>

// ---------------------------------------------------------------------------
// GQA block: y = Attn(x Wq + bq, x Wk + bk, x Wv + bv) Wo + bo
// B=2 S=2048 E=2048 H=16 G=4 D=128 R=4.  All GEMMs in bf16 MFMA, fp32 accum.
// R1: swapped QK^T attention (P in-register), V pre-transpose, defer-max.
// R2: GEMM 8-wave pipeline, 4-deep LDS ring, counted vmcnt, raw s_barrier.
// R3: QKV GEMM 256x192 (grid 256); attn K/V dbuf 64KB (1 barrier).
// R4-R9: six attn occupancy/staging variants regressed; R3 attn = optimum.
// R10: no-max softmax; V-transpose fused into QKV GEMM. [attn 82.2, tot 190.7]
// R11: GEMM LDS swizzle NEUTRAL -> conflict diagnosis retracted.
// R12: GEMM phase-split (T3 coarse port) REGRESSED +11us (m196 failure mode:
//     8 barriers/K-tile without fine interleave). GEMM scheduling CLOSED;
//     K-loop reverted to R10 form.
// R13: prep kernels fused into ONE launch (cast_x | W-transpose | bias);
//     attn XCD swizzle (T1): XCD c owns bh panels 4c..4c+3 -> each K/V
//     panel resident in exactly one L2.
// ---------------------------------------------------------------------------

typedef __attribute__((ext_vector_type(8))) short bf16x8;
typedef __attribute__((ext_vector_type(4))) short bf16x4;
typedef __attribute__((ext_vector_type(4))) float f32x4;

#define MFMA_16x16x32(a, b, c) __builtin_amdgcn_mfma_f32_16x16x32_bf16((a), (b), (c), 0, 0, 0)

__device__ __forceinline__ unsigned short f2bf(float x) {
  union { float f; unsigned int u; } c;
  c.f = x;
  unsigned int u = c.u;
  return (unsigned short)((u + 0x7fffu + ((u >> 16) & 1u)) >> 16);  // RNE
}

__device__ __forceinline__ unsigned short f2bf_hw(float x) {
  __hip_bfloat16 h = __float2bfloat16(x);
  union { __hip_bfloat16 h; unsigned short u; } c;
  c.h = h;
  return c.u;
}

__device__ __forceinline__ void gload_lds16(const void* g, void* l) {
  __builtin_amdgcn_global_load_lds(
      (const __attribute__((address_space(1))) unsigned int*)g,
      (__attribute__((address_space(3))) unsigned int*)l, 16, 0, 0);
}

// ---------------------------------------------------------------------------
// Fused prep: blocks [0,4096) cast x -> bf16; [4096,14336) transpose-cast the
// four weight matrices; [14336,14348) concat bias. One launch, no gaps.
__global__ void prep_kernel(const float* __restrict__ x,
                            const float* __restrict__ Wq,
                            const float* __restrict__ Wk,
                            const float* __restrict__ Wv,
                            const float* __restrict__ Wo,
                            const float* __restrict__ bq,
                            const float* __restrict__ bk,
                            const float* __restrict__ bv,
                            unsigned short* __restrict__ xb,
                            unsigned short* __restrict__ WqkvT,
                            unsigned short* __restrict__ WoT,
                            float* __restrict__ bqkv) {
  __shared__ float t[32][33];
  const int bid = blockIdx.x;
  const int tid = threadIdx.x;

  if (bid < 4096) {
    // ---- cast x -> bf16, 8 elems/thread ----
    const long i = ((long)bid * 256 + tid) * 8;
    float4 a = *reinterpret_cast<const float4*>(x + i);
    float4 b = *reinterpret_cast<const float4*>(x + i + 4);
    union { unsigned short s[8]; bf16x8 v; } o;
    o.s[0] = f2bf(a.x); o.s[1] = f2bf(a.y); o.s[2] = f2bf(a.z); o.s[3] = f2bf(a.w);
    o.s[4] = f2bf(b.x); o.s[5] = f2bf(b.y); o.s[6] = f2bf(b.z); o.s[7] = f2bf(b.w);
    *reinterpret_cast<bf16x8*>(xb + i) = o.v;
    return;
  }
  if (bid < 14336) {
    // ---- transpose-cast weights ----
    const int pb = bid - 4096;
    const int ng = (pb % 160) * 32;
    const int k0 = (pb / 160) * 32;
    const int tx = tid & 31, ty = tid >> 5;
    const float* src;
    int srcN, n0;
    unsigned short* dst;
    if (ng < 2048)      { src = Wq; srcN = 2048; n0 = ng;        dst = WqkvT + (size_t)ng * 2048; }
    else if (ng < 2560) { src = Wk; srcN = 512;  n0 = ng - 2048; dst = WqkvT + (size_t)ng * 2048; }
    else if (ng < 3072) { src = Wv; srcN = 512;  n0 = ng - 2560; dst = WqkvT + (size_t)ng * 2048; }
    else                { src = Wo; srcN = 2048; n0 = ng - 3072; dst = WoT + (size_t)(ng - 3072) * 2048; }
#pragma unroll
    for (int i = 0; i < 4; i++)
      t[ty + i * 8][tx] = src[(size_t)(k0 + ty + i * 8) * srcN + n0 + tx];
    __syncthreads();
#pragma unroll
    for (int i = 0; i < 4; i++)
      dst[(size_t)(ty + i * 8) * 2048 + k0 + tx] = f2bf(t[tx][ty + i * 8]);
    return;
  }
  // ---- bias concat ----
  const int i = (bid - 14336) * 256 + tid;
  if (i < 3072)
    bqkv[i] = (i < 2048) ? bq[i] : (i < 2560 ? bk[i - 2048] : bv[i - 2560]);
}

// ---------------------------------------------------------------------------
// Pipelined GEMM (R10 form: ring-4 LDS, 2-ahead prefetch, counted vmcnt,
// one barrier per K-tile, stage split around the two MFMA halves).
// For the QKV instance (vt != nullptr), columns gc >= 2560 are V: written
// (with kv-permutation c()) to vt instead of C.
template <int AROWS, int BROWS, bool BF16OUT>
__global__ __launch_bounds__(512, 2)
void gemm_pipe_kernel(const unsigned short* __restrict__ A,
                      const unsigned short* __restrict__ Bt,
                      const float* __restrict__ bias,
                      void* __restrict__ C, int M, int N, int K,
                      float qscale, int qcols,
                      unsigned short* __restrict__ vt) {
  constexpr int FM = AROWS / 32;
  constexpr int FN = BROWS / 64;
  constexpr int HFM = FM / 2;
  constexpr int TC = (AROWS + BROWS) * 4;
  constexpr int LOADS = (TC + 511) / 512;
  constexpr int PC = LOADS * 512;
  constexpr int BUFE = PC * 8;
  constexpr int BOFF = AROWS * 32;
  constexpr int LH = (LOADS + 1) / 2;
  __shared__ unsigned short lds[4 * BUFE];

  const int tid = threadIdx.x;
  const int w = tid >> 6, l = tid & 63, lg = l >> 4, ll = l & 15;
  const int wm = w >> 2, wn = w & 3;
  const int m0 = blockIdx.y * AROWS;
  const int n0 = blockIdx.x * BROWS;
  const int NT = K >> 5;

  const f32x4 fz = {0.f, 0.f, 0.f, 0.f};
  f32x4 acc[FM][FN];
#pragma unroll
  for (int i = 0; i < FM; i++)
#pragma unroll
    for (int j = 0; j < FN; j++) acc[i][j] = fz;

  const unsigned short* gsrc[LOADS];
#pragma unroll
  for (int i = 0; i < LOADS; ++i) {
    const int c = tid + 512 * i;
    if (c < AROWS * 4) {
      gsrc[i] = A + (size_t)(m0 + (c >> 2)) * K + (c & 3) * 8;
    } else if (c < TC) {
      const int cb = c - AROWS * 4;
      gsrc[i] = Bt + (size_t)(n0 + (cb >> 2)) * K + (cb & 3) * 8;
    } else {
      gsrc[i] = Bt + (size_t)n0 * K;  // dummy, lands in pad region
    }
  }

  auto stage_lo = [&](int t) {
    unsigned short* dst = &lds[(t & 3) * BUFE + tid * 8];
#pragma unroll
    for (int i = 0; i < LH; ++i) gload_lds16(gsrc[i] + t * 32, dst + i * 4096);
  };
  auto stage_hi = [&](int t) {
    unsigned short* dst = &lds[(t & 3) * BUFE + tid * 8];
#pragma unroll
    for (int i = LH; i < LOADS; ++i) gload_lds16(gsrc[i] + t * 32, dst + i * 4096);
  };

  stage_lo(0); stage_hi(0);
  stage_lo(1); stage_hi(1);

  for (int t = 0; t < NT; ++t) {
    if (t + 1 < NT) {
      if constexpr (LOADS == 4)
        asm volatile("s_waitcnt vmcnt(4)" ::: "memory");
      else if constexpr (LOADS == 3)
        asm volatile("s_waitcnt vmcnt(3)" ::: "memory");
      else
        asm volatile("s_waitcnt vmcnt(0)" ::: "memory");
    } else {
      asm volatile("s_waitcnt vmcnt(0)" ::: "memory");
    }
    __builtin_amdgcn_s_barrier();
    const unsigned short* bufp = &lds[(t & 3) * BUFE];

    bf16x8 bfrag[FN], afrag[HFM];
#pragma unroll
    for (int ni = 0; ni < FN; ++ni)
      bfrag[ni] = *reinterpret_cast<const bf16x8*>(
          &bufp[BOFF + (wn * FN * 16 + ni * 16 + ll) * 32 + lg * 8]);
#pragma unroll
    for (int mi = 0; mi < HFM; ++mi)
      afrag[mi] = *reinterpret_cast<const bf16x8*>(
          &bufp[(wm * (AROWS / 2) + mi * 16 + ll) * 32 + lg * 8]);
    if (t + 2 < NT) stage_lo(t + 2);
    __builtin_amdgcn_s_setprio(1);
#pragma unroll
    for (int mi = 0; mi < HFM; ++mi)
#pragma unroll
      for (int ni = 0; ni < FN; ++ni)
        acc[mi][ni] = MFMA_16x16x32(afrag[mi], bfrag[ni], acc[mi][ni]);
    __builtin_amdgcn_s_setprio(0);

#pragma unroll
    for (int mi = 0; mi < HFM; ++mi)
      afrag[mi] = *reinterpret_cast<const bf16x8*>(
          &bufp[(wm * (AROWS / 2) + (HFM + mi) * 16 + ll) * 32 + lg * 8]);
    if (t + 2 < NT) stage_hi(t + 2);
    __builtin_amdgcn_s_setprio(1);
#pragma unroll
    for (int mi = 0; mi < HFM; ++mi)
#pragma unroll
      for (int ni = 0; ni < FN; ++ni)
        acc[HFM + mi][ni] = MFMA_16x16x32(afrag[mi], bfrag[ni], acc[HFM + mi][ni]);
    __builtin_amdgcn_s_setprio(0);
  }

#pragma unroll
  for (int mi = 0; mi < FM; ++mi) {
#pragma unroll
    for (int ni = 0; ni < FN; ++ni) {
      const int gc = n0 + wn * FN * 16 + ni * 16 + ll;
      const float bv = bias[gc];
      const float sc = (gc < qcols) ? qscale : 1.0f;
      if (BF16OUT && vt != nullptr && gc >= 2560) {
        // V column: write to Vt[(b*512 + d)][sp(s)] with c() permutation
        const int gr0 = m0 + wm * (AROWS / 2) + mi * 16 + 4 * lg;
        const int bb = gr0 >> 11, s = gr0 & 2047;
        const int spb = (s & ~63) | ((s & 12) << 1) | (((s >> 4) & 1) << 2) | (s & 32);
        union { unsigned short u[4]; bf16x4 v4; } ov;
#pragma unroll
        for (int r = 0; r < 4; ++r) ov.u[r] = f2bf(acc[mi][ni][r] + bv);
        *reinterpret_cast<bf16x4*>(
            &vt[(size_t)(bb * 512 + gc - 2560) * 2048 + spb]) = ov.v4;
      } else {
#pragma unroll
        for (int r = 0; r < 4; ++r) {
          const int gr = m0 + wm * (AROWS / 2) + mi * 16 + 4 * lg + r;
          const float v = (acc[mi][ni][r] + bv) * sc;
          if constexpr (BF16OUT)
            ((unsigned short*)C)[(size_t)gr * N + gc] = f2bf(v);
          else
            ((float*)C)[(size_t)gr * N + gc] = v;
        }
      }
    }
  }
}

// ---------------------------------------------------------------------------
// Flash attention (R10 core + T1 XCD swizzle): 4 waves x 32 q, KVBLK=64,
// 512 blocks. Linear block id remapped so XCD c (dispatch round-robin lid%8)
// owns work ids c*64..c*64+63 = bh panels 4c..4c+3 -> K/V panel lives in one
// L2. K/V dbuf 64KB (reg-staged, 1 barrier/tile). No-max softmax.
__global__ __launch_bounds__(256, 2)
void attn_kernel(const unsigned short* __restrict__ QKV,
                 const unsigned short* __restrict__ Vt,
                 unsigned short* __restrict__ AO) {
  __shared__ unsigned short Klds[2][64 * 128];  // [kv][d]  elem ^ ((kv&7)<<3)
  __shared__ unsigned short Vlds[2][128 * 64];  // [d][c]   elem ^ ((d&7)<<3)

  const int tid = threadIdx.x;
  const int w = tid >> 6, l = tid & 63, lg = l >> 4, ll = l & 15;
  // T1 XCD swizzle: lid -> (lid&7)*64 + lid/8 (nwg=512, bijective)
  const int lid = blockIdx.y * 16 + blockIdx.x;
  const int swz = (lid & 7) * 64 + (lid >> 3);
  const int bx = swz & 15, bh = swz >> 4;
  const int b = bh >> 4, h = bh & 15, g = h >> 2;
  const int q0 = bx * 128 + w * 32;
  const size_t row_base = (size_t)b * 2048 * 2560;
  const unsigned short* Vg = Vt + (size_t)(b * 512 + g * 128) * 2048;

  bf16x8 qf[2][4];
#pragma unroll
  for (int mi = 0; mi < 2; mi++)
#pragma unroll
    for (int ds = 0; ds < 4; ds++)
      qf[mi][ds] = *reinterpret_cast<const bf16x8*>(
          QKV + row_base + (size_t)(q0 + mi * 16 + ll) * 2560 + h * 128 + ds * 32 + 8 * lg);

  const f32x4 fz = {0.f, 0.f, 0.f, 0.f};
  f32x4 o[8][2];
#pragma unroll
  for (int di = 0; di < 8; di++)
#pragma unroll
    for (int mi = 0; mi < 2; mi++) o[di][mi] = fz;
  float pssum[2] = {0.f, 0.f};

  const int krow = tid >> 4, kc8 = tid & 15;
  const int vrow = tid >> 3, vc8 = tid & 7;
  const unsigned short* Kg = QKV + row_base + 2048 + g * 128 + kc8 * 8 + (size_t)krow * 2560;
  int klo[4], vlo[4];
#pragma unroll
  for (int i = 0; i < 4; i++) {
    const int kr = krow + 16 * i;
    klo[i] = (kr * 128 + kc8 * 8) ^ ((kr & 7) << 3);
    const int vr = vrow + 32 * i;
    vlo[i] = (vr * 64 + vc8 * 8) ^ ((vr & 7) << 3);
  }

  bf16x8 kreg[4], vreg[4];
#pragma unroll
  for (int i = 0; i < 4; i++) {
    kreg[i] = *reinterpret_cast<const bf16x8*>(Kg + (size_t)(16 * i) * 2560);
    vreg[i] = *reinterpret_cast<const bf16x8*>(Vg + (size_t)(vrow + 32 * i) * 2048 + vc8 * 8);
  }

  for (int kt = 0; kt < 32; kt++) {
    const int cb = kt & 1;
#pragma unroll
    for (int i = 0; i < 4; i++) *reinterpret_cast<bf16x8*>(&Klds[cb][klo[i]]) = kreg[i];
#pragma unroll
    for (int i = 0; i < 4; i++) *reinterpret_cast<bf16x8*>(&Vlds[cb][vlo[i]]) = vreg[i];
    __syncthreads();

    if (kt + 1 < 32) {
#pragma unroll
      for (int i = 0; i < 4; i++) {
        kreg[i] = *reinterpret_cast<const bf16x8*>(
            Kg + (size_t)((kt + 1) * 64 + 16 * i) * 2560);
        vreg[i] = *reinterpret_cast<const bf16x8*>(
            Vg + (size_t)(vrow + 32 * i) * 2048 + (kt + 1) * 64 + vc8 * 8);
      }
    }

    f32x4 st[4][2];
#pragma unroll
    for (int ni = 0; ni < 4; ni++)
#pragma unroll
      for (int mi = 0; mi < 2; mi++) st[ni][mi] = fz;
#pragma unroll
    for (int ds = 0; ds < 4; ds++) {
      bf16x8 kf[4];
#pragma unroll
      for (int ni = 0; ni < 4; ni++) {
        const int kr = ni * 16 + ll;
        kf[ni] = *reinterpret_cast<const bf16x8*>(
            &Klds[cb][(kr * 128 + ds * 32 + 8 * lg) ^ ((kr & 7) << 3)]);
      }
      __builtin_amdgcn_s_setprio(1);
#pragma unroll
      for (int ni = 0; ni < 4; ni++)
#pragma unroll
        for (int mi = 0; mi < 2; mi++)
          st[ni][mi] = MFMA_16x16x32(kf[ni], qf[mi][ds], st[ni][mi]);
      __builtin_amdgcn_s_setprio(0);
    }

#pragma unroll
    for (int ni = 0; ni < 4; ni++)
#pragma unroll
      for (int mi = 0; mi < 2; mi++)
#pragma unroll
        for (int r = 0; r < 4; r++) {
          const float pv = __builtin_amdgcn_exp2f(st[ni][mi][r]);
          st[ni][mi][r] = pv;
          pssum[mi] += pv;
        }

    bf16x8 pf[2][2];
#pragma unroll
    for (int mi = 0; mi < 2; mi++)
#pragma unroll
      for (int ks = 0; ks < 2; ks++)
#pragma unroll
        for (int j = 0; j < 4; j++) {
          pf[mi][ks][j]     = (short)f2bf_hw(st[2 * ks][mi][j]);
          pf[mi][ks][4 + j] = (short)f2bf_hw(st[2 * ks + 1][mi][j]);
        }

    __builtin_amdgcn_s_setprio(1);
#pragma unroll
    for (int ks = 0; ks < 2; ks++)
#pragma unroll
      for (int di = 0; di < 8; di++) {
        const int dr = di * 16 + ll;
        const bf16x8 vf = *reinterpret_cast<const bf16x8*>(
            &Vlds[cb][(dr * 64 + ks * 32 + 8 * lg) ^ ((dr & 7) << 3)]);
        o[di][0] = MFMA_16x16x32(vf, pf[0][ks], o[di][0]);
        o[di][1] = MFMA_16x16x32(vf, pf[1][ks], o[di][1]);
      }
    __builtin_amdgcn_s_setprio(0);
  }

  float invl[2];
#pragma unroll
  for (int mi = 0; mi < 2; mi++) {
    float s = pssum[mi];
    s += __shfl_xor(s, 16, 64);
    s += __shfl_xor(s, 32, 64);
    invl[mi] = 1.0f / s;
  }
#pragma unroll
  for (int mi = 0; mi < 2; mi++) {
    const size_t rowoff = (size_t)(b * 2048 + q0 + mi * 16 + ll) * 2048 + h * 128;
#pragma unroll
    for (int di = 0; di < 8; di++) {
      union { unsigned short s[4]; bf16x4 v; } ov;
#pragma unroll
      for (int r = 0; r < 4; r++) ov.s[r] = f2bf_hw(o[di][mi][r] * invl[mi]);
      *reinterpret_cast<bf16x4*>(&AO[rowoff + di * 16 + 4 * lg]) = ov.v;
    }
  }
}

// ---------------------------------------------------------------------------
extern "C" void kernel_launch(void* const* d_in, const int* in_sizes, int n_in,
                              void* d_out, int out_size, void* d_ws, size_t ws_size,
                              hipStream_t stream) {
  const float* x  = (const float*)d_in[0];
  const float* Wq = (const float*)d_in[1];
  const float* bq = (const float*)d_in[2];
  const float* Wk = (const float*)d_in[3];
  const float* bk = (const float*)d_in[4];
  const float* Wv = (const float*)d_in[5];
  const float* bv = (const float*)d_in[6];
  const float* Wo = (const float*)d_in[7];
  const float* bo = (const float*)d_in[8];
  float* out = (float*)d_out;

  // workspace carve (bf16 elems), total ~76 MB:
  unsigned short* xb    = (unsigned short*)d_ws;               // 4096*2048
  unsigned short* WqkvT = xb + (size_t)4096 * 2048;            // 3072*2048
  unsigned short* WoT   = WqkvT + (size_t)3072 * 2048;         // 2048*2048
  unsigned short* QKV   = WoT + (size_t)2048 * 2048;           // 4096*2560 (Q|K only)
  unsigned short* AO    = QKV + (size_t)4096 * 2560;           // 4096*2048
  unsigned short* Vt    = AO + (size_t)4096 * 2048;            // 1024*2048
  float* bqkv = (float*)(Vt + (size_t)1024 * 2048);            // 3072 f32

  const float QSC2 = 0.08838834764831845f * 1.4426950408889634f;  // 1/sqrt(D)*log2e

  // fused prep: cast x | transpose weights | concat bias
  prep_kernel<<<14348, 256, 0, stream>>>(x, Wq, Wk, Wv, Wo, bq, bk, bv,
                                         xb, WqkvT, WoT, bqkv);
  // QKV GEMM: Q,K -> QKV (stride 2560, Q pre-scaled by QSC2); V -> Vt fused.
  gemm_pipe_kernel<256, 192, true><<<dim3(16, 16), 512, 0, stream>>>(
      xb, WqkvT, bqkv, QKV, 4096, 2560, 2048, QSC2, 2048, Vt);
  // flash attention -> AO bf16 [4096][2048]
  attn_kernel<<<dim3(16, 32), 256, 0, stream>>>(QKV, Vt, AO);
  // out = AO @ WoT^T + bo -> fp32
  gemm_pipe_kernel<128, 256, false><<<dim3(8, 32), 512, 0, stream>>>(
      AO, WoT, bo, out, 4096, 2048, 2048, 1.0f, 0, nullptr);
}